// Round 1
// baseline (4839.466 us; speedup 1.0000x reference)
//
#include <hip/hip_runtime.h>

// NeuralMemory scan: B=4, S=256, H=128, EXP=2, DEPTH=2.
// Design: params never materialized (p_t = p0*(1-a_t) + m_t). Momentum m and
// p0 live in REGISTERS, sharded over the 256 hidden units across 4 WGs/batch
// (64 units each). Cross-WG: 3 vector reductions per step via agent-scope
// atomics + monotonic counter barriers in d_ws. Grid = 16 blocks x 512 thr.

constexpr int HD  = 128;   // H
constexpr int SEQ = 256;   // S
constexpr int NB  = 4;     // B
constexpr int ED  = 256;   // H*EXP
constexpr int CW  = 64;    // hidden units per WG per layer (ED/NWG)
constexpr int NWG = 4;     // workgroups per batch

__device__ __forceinline__ float sigm(float x){ return 1.0f/(1.0f+__expf(-x)); }

// ---------------- kernel 1: q/k/v + gate scalars ----------------
__global__ __launch_bounds__(128) void qkv_kernel(
    const float* __restrict__ x,
    const float* __restrict__ Wq, const float* __restrict__ Wk, const float* __restrict__ Wv,
    const float* __restrict__ w_lr, const float* __restrict__ b_lr,
    const float* __restrict__ w_fg, const float* __restrict__ b_fg,
    const float* __restrict__ w_mo, const float* __restrict__ b_mo,
    float* __restrict__ qb, float* __restrict__ kb, float* __restrict__ vb,
    float* __restrict__ thb, float* __restrict__ alb, float* __restrict__ etb)
{
  const int bs = blockIdx.x;          // b*SEQ + s
  const int o  = threadIdx.x;         // 0..127
  __shared__ float xl[HD];
  __shared__ float rb[HD];
  xl[o] = x[(size_t)bs*HD + o];
  __syncthreads();

  float aq=0.f, ak=0.f, av=0.f;
  #pragma unroll 8
  for (int i=0;i<HD;i++){
    float xi = xl[i];
    aq = fmaf(xi, Wq[i*HD+o], aq);
    ak = fmaf(xi, Wk[i*HD+o], ak);
    av = fmaf(xi, Wv[i*HD+o], av);
  }
  float sq_ = aq*sigm(aq);
  float sk_ = ak*sigm(ak);
  float sv_ = av*sigm(av);

  auto bsum = [&](float v)->float {
    rb[o] = v; __syncthreads();
    for (int st=64; st>0; st>>=1){
      if (o < st) rb[o] += rb[o+st];
      __syncthreads();
    }
    float r = rb[0];
    __syncthreads();
    return r;
  };

  float nq = bsum(sq_*sq_);
  float nk = bsum(sk_*sk_);
  float dl = bsum(xl[o]*w_lr[o]);
  float df = bsum(xl[o]*w_fg[o]);
  float dm = bsum(xl[o]*w_mo[o]);

  qb[(size_t)bs*HD+o] = sq_ / fmaxf(sqrtf(nq), 1e-12f);
  kb[(size_t)bs*HD+o] = sk_ / fmaxf(sqrtf(nk), 1e-12f);
  vb[(size_t)bs*HD+o] = sv_;
  if (o==0){
    thb[bs] = sigm(dl + b_lr[0]) * 0.01f;   // MAX_LR
    alb[bs] = sigm(df + b_fg[0]);
    etb[bs] = sigm(dm + b_mo[0]);
  }
}

// ---------------- kernel 2: the sequential scan ----------------
__global__ __launch_bounds__(512, 2) void scan_kernel(
    const float* __restrict__ w1_0g, const float* __restrict__ b1_0g,
    const float* __restrict__ w2_0g, const float* __restrict__ b2_0g,
    const float* __restrict__ mw1_0g, const float* __restrict__ mb1_0g,
    const float* __restrict__ mw2_0g, const float* __restrict__ mb2_0g,
    const float* __restrict__ w1_1g, const float* __restrict__ b1_1g,
    const float* __restrict__ w2_1g, const float* __restrict__ b2_1g,
    const float* __restrict__ mw1_1g, const float* __restrict__ mb1_1g,
    const float* __restrict__ mw2_1g, const float* __restrict__ mb2_1g,
    const float* __restrict__ qbuf, const float* __restrict__ kbuf, const float* __restrict__ vbuf,
    const float* __restrict__ thb, const float* __restrict__ alb, const float* __restrict__ etb,
    float* __restrict__ red, unsigned* __restrict__ cnt, float* __restrict__ out)
{
  const int bid = blockIdx.x;
  const int b   = bid & 3;     // batch (blockIdx%4 -> spreads a batch's WGs over XCDs)
  const int wg  = bid >> 2;    // 0..3 within batch
  const int tid = threadIdx.x;
  const int iG  = tid & 31;    // i-group (w1) / o-group (w2)
  const int jG  = tid >> 5;    // j-group 0..15
  const int i0  = iG*4;
  const int j0  = jG*4;
  const int c0  = wg*CW;

  // ---- register-resident parameter slices: 64 m + 64 p0 per thread ----
  float mw1[2][16], pw1[2][16], mw2[2][16], pw2[2][16];
  {
    const float* w1s[2]  = {w1_0g,  w1_1g};
    const float* mw1s[2] = {mw1_0g, mw1_1g};
    const float* w2s[2]  = {w2_0g,  w2_1g};
    const float* mw2s[2] = {mw2_0g, mw2_1g};
    #pragma unroll
    for (int l=0;l<2;l++){
      #pragma unroll
      for (int jj=0;jj<4;jj++){
        #pragma unroll
        for (int ii=0;ii<4;ii++){
          int gi1 = (i0+ii)*ED + (c0+j0+jj);
          pw1[l][jj*4+ii] = w1s[l][gi1];
          mw1[l][jj*4+ii] = mw1s[l][gi1];
          int gi2 = (c0+j0+jj)*HD + (i0+ii);
          pw2[l][jj*4+ii] = w2s[l][gi2];
          mw2[l][jj*4+ii] = mw2s[l][gi2];
        }
      }
    }
  }

  __shared__ float kvec[HD], qvec[HD], vvec[HD];
  __shared__ float u1k[CW], u2k[CW], s1k[CW], s2k[CW], sq1[CW], sq2[CW];
  __shared__ float h1k[HD], h1q[HD], h2k[HD];
  __shared__ float g2v[HD], gh1[HD], gu1[CW], gu2[CW];
  __shared__ float redbuf[8][256];
  __shared__ float b1p[2][CW], b1m[2][CW], b2p[2][32], b2m[2][32];
  __shared__ float scal[8];   // [0]=theta [1]=alpha [2]=eta [5]=cA [6]=cB

  if (tid < CW){
    b1p[0][tid] = b1_0g[c0+tid]; b1m[0][tid] = mb1_0g[c0+tid];
    b1p[1][tid] = b1_1g[c0+tid]; b1m[1][tid] = mb1_1g[c0+tid];
  } else if (tid < CW+32){
    int oo = tid - CW;
    b2p[0][oo] = b2_0g[wg*32+oo]; b2m[0][oo] = mb2_0g[wg*32+oo];
    b2p[1][oo] = b2_1g[wg*32+oo]; b2m[1][oo] = mb2_1g[wg*32+oo];
  }

  float* slotB  = red + ((b*3+0)*NWG + wg)*256;
  float* slotF1 = red + ((b*3+1)*NWG + wg)*256;
  float* slotF2 = red + ((b*3+2)*NWG + wg)*256;
  unsigned* cB_  = cnt + (b*4+0);
  unsigned* cF1_ = cnt + (b*4+1);
  unsigned* cF2_ = cnt + (b*4+2);
  unsigned tgtb=4, tgtf1=4, tgtf2=4;

  auto wgbar = [&](unsigned* c, unsigned target){
    __syncthreads();                 // drains all threads' vmem stores
    if (tid==0){
      __threadfence();
      __hip_atomic_fetch_add(c, 1u, __ATOMIC_RELEASE, __HIP_MEMORY_SCOPE_AGENT);
      while (__hip_atomic_load(c, __ATOMIC_RELAXED, __HIP_MEMORY_SCOPE_AGENT) < target) { }
      __threadfence();
    }
    __syncthreads();
  };

  auto redload = [&](int type, int w, int idx)->float{
    float* p = red + ((b*3+type)*NWG + w)*256 + idx;
    return __hip_atomic_load(p, __ATOMIC_RELAXED, __HIP_MEMORY_SCOPE_AGENT);
  };

  // merged forward of q_t (output) and k_{t+1} (next step's activations)
  auto fwdDual = [&](int t, bool writeOut){
    float cA = scal[5], cB = scal[6];
    // ---- layer0 u ----
    {
      float aq[4]={0,0,0,0}, ak[4]={0,0,0,0};
      #pragma unroll
      for (int ii=0;ii<4;ii++){
        float qi = qvec[i0+ii], ki = kvec[i0+ii];
        #pragma unroll
        for (int jj=0;jj<4;jj++){
          float w = fmaf(pw1[0][jj*4+ii], cA, mw1[0][jj*4+ii]*cB);
          aq[jj] = fmaf(qi, w, aq[jj]);
          ak[jj] = fmaf(ki, w, ak[jj]);
        }
      }
      #pragma unroll
      for (int d=1; d<32; d<<=1){
        #pragma unroll
        for (int jj=0;jj<4;jj++){
          aq[jj] += __shfl_xor(aq[jj], d, 64);
          ak[jj] += __shfl_xor(ak[jj], d, 64);
        }
      }
      if (iG==0){
        #pragma unroll
        for (int jj=0;jj<4;jj++){
          int j=j0+jj;
          float bb = fmaf(b1p[0][j], cA, b1m[0][j]*cB);
          float uq = aq[jj]+bb, uk = ak[jj]+bb;
          u1k[j]=uk; s1k[j]=uk*sigm(uk); sq1[j]=uq*sigm(uq);
        }
      }
    }
    __syncthreads();
    // ---- layer0 s@w2 partials ----
    {
      float aq[4]={0,0,0,0}, ak[4]={0,0,0,0};
      #pragma unroll
      for (int jj=0;jj<4;jj++){
        float sjq = sq1[j0+jj], sjk = s1k[j0+jj];
        #pragma unroll
        for (int oo=0;oo<4;oo++){
          float w = fmaf(pw2[0][jj*4+oo], cA, mw2[0][jj*4+oo]*cB);
          aq[oo] = fmaf(sjq, w, aq[oo]);
          ak[oo] = fmaf(sjk, w, ak[oo]);
        }
      }
      #pragma unroll
      for (int oo=0;oo<4;oo++){
        aq[oo] += __shfl_xor(aq[oo], 32, 64);
        ak[oo] += __shfl_xor(ak[oo], 32, 64);
      }
      if ((tid & 32)==0){
        int wv = tid>>6;
        #pragma unroll
        for (int oo=0;oo<4;oo++){
          redbuf[wv][i0+oo]     = aq[oo];
          redbuf[wv][128+i0+oo] = ak[oo];
        }
      }
    }
    __syncthreads();
    if (tid < 256){
      float p=0.f;
      #pragma unroll
      for (int w_=0; w_<8; w_++) p += redbuf[w_][tid];
      int o = tid & 127;
      if (o >= wg*32 && o < wg*32+32){
        int oo = o - wg*32;
        p += fmaf(b2p[0][oo], cA, b2m[0][oo]*cB);   // owner adds b2 shard
      }
      __hip_atomic_store(&slotF1[tid], p, __ATOMIC_RELAXED, __HIP_MEMORY_SCOPE_AGENT);
    }
    wgbar(cF1_, tgtf1); tgtf1 += 4;
    if (tid < 256){
      int o = tid & 127;
      float s0 = (tid<128) ? qvec[o] : kvec[o];     // residual
      #pragma unroll
      for (int w_=0; w_<NWG; w_++) s0 += redload(1, w_, tid);
      if (tid<128) h1q[o]=s0; else h1k[o]=s0;
    }
    __syncthreads();
    // ---- layer1 u ----
    {
      float aq[4]={0,0,0,0}, ak[4]={0,0,0,0};
      #pragma unroll
      for (int ii=0;ii<4;ii++){
        float qi = h1q[i0+ii], ki = h1k[i0+ii];
        #pragma unroll
        for (int jj=0;jj<4;jj++){
          float w = fmaf(pw1[1][jj*4+ii], cA, mw1[1][jj*4+ii]*cB);
          aq[jj] = fmaf(qi, w, aq[jj]);
          ak[jj] = fmaf(ki, w, ak[jj]);
        }
      }
      #pragma unroll
      for (int d=1; d<32; d<<=1){
        #pragma unroll
        for (int jj=0;jj<4;jj++){
          aq[jj] += __shfl_xor(aq[jj], d, 64);
          ak[jj] += __shfl_xor(ak[jj], d, 64);
        }
      }
      if (iG==0){
        #pragma unroll
        for (int jj=0;jj<4;jj++){
          int j=j0+jj;
          float bb = fmaf(b1p[1][j], cA, b1m[1][j]*cB);
          float uq = aq[jj]+bb, uk = ak[jj]+bb;
          u2k[j]=uk; s2k[j]=uk*sigm(uk); sq2[j]=uq*sigm(uq);
        }
      }
    }
    __syncthreads();
    // ---- layer1 s@w2 partials ----
    {
      float aq[4]={0,0,0,0}, ak[4]={0,0,0,0};
      #pragma unroll
      for (int jj=0;jj<4;jj++){
        float sjq = sq2[j0+jj], sjk = s2k[j0+jj];
        #pragma unroll
        for (int oo=0;oo<4;oo++){
          float w = fmaf(pw2[1][jj*4+oo], cA, mw2[1][jj*4+oo]*cB);
          aq[oo] = fmaf(sjq, w, aq[oo]);
          ak[oo] = fmaf(sjk, w, ak[oo]);
        }
      }
      #pragma unroll
      for (int oo=0;oo<4;oo++){
        aq[oo] += __shfl_xor(aq[oo], 32, 64);
        ak[oo] += __shfl_xor(ak[oo], 32, 64);
      }
      if ((tid & 32)==0){
        int wv = tid>>6;
        #pragma unroll
        for (int oo=0;oo<4;oo++){
          redbuf[wv][i0+oo]     = aq[oo];
          redbuf[wv][128+i0+oo] = ak[oo];
        }
      }
    }
    __syncthreads();
    if (tid < 256){
      float p=0.f;
      #pragma unroll
      for (int w_=0; w_<8; w_++) p += redbuf[w_][tid];
      int o = tid & 127;
      if (o >= wg*32 && o < wg*32+32){
        int oo = o - wg*32;
        p += fmaf(b2p[1][oo], cA, b2m[1][oo]*cB);
      }
      __hip_atomic_store(&slotF2[tid], p, __ATOMIC_RELAXED, __HIP_MEMORY_SCOPE_AGENT);
    }
    wgbar(cF2_, tgtf2); tgtf2 += 4;
    if (tid < 256){
      int o = tid & 127;
      float s0 = (tid<128) ? h1q[o] : h1k[o];
      #pragma unroll
      for (int w_=0; w_<NWG; w_++) s0 += redload(2, w_, tid);
      if (tid<128){
        if (writeOut && o >= wg*32 && o < wg*32+32)
          out[((size_t)(b*SEQ + t))*HD + o] = s0;   // y[b,t,:] shard
      } else {
        h2k[o] = s0;                                 // pred for next bwd
      }
    }
  };

  // ---- prologue: forward k_0 with cp = p0 exactly (cA=1, cB=0) ----
  if (tid < HD){
    kvec[tid] = kbuf[((size_t)b*SEQ + 0)*HD + tid];
    qvec[tid] = 0.f;
  }
  if (tid==0){ scal[5]=1.f; scal[6]=0.f; }
  __syncthreads();
  fwdDual(0, false);

  for (int t=0; t<SEQ; ++t){
    if (tid < HD) vvec[tid] = vbuf[((size_t)b*SEQ + t)*HD + tid];
    if (tid==0){
      scal[0]=thb[b*SEQ+t]; scal[1]=alb[b*SEQ+t]; scal[2]=etb[b*SEQ+t];
    }
    __syncthreads();
    float cAp = scal[5], cBp = scal[6];   // coefs of p_{t-1} (prev fwd)
    if (tid < HD) g2v[tid] = (2.0f/128.0f)*(h2k[tid]-vvec[tid]);
    __syncthreads();
    // gu2 = (g2 @ w2b^T) * silu'(u2)
    {
      float acc[4]={0,0,0,0};
      #pragma unroll
      for (int oo=0;oo<4;oo++){
        float go = g2v[i0+oo];
        #pragma unroll
        for (int jj=0;jj<4;jj++){
          float w = fmaf(pw2[1][jj*4+oo], cAp, mw2[1][jj*4+oo]*cBp);
          acc[jj] = fmaf(go, w, acc[jj]);
        }
      }
      #pragma unroll
      for (int d=1; d<32; d<<=1){
        #pragma unroll
        for (int jj=0;jj<4;jj++) acc[jj] += __shfl_xor(acc[jj], d, 64);
      }
      if (iG==0){
        #pragma unroll
        for (int jj=0;jj<4;jj++){
          int j=j0+jj; float u=u2k[j]; float sg=sigm(u);
          gu2[j] = acc[jj]*sg*fmaf(u, 1.f-sg, 1.f);
        }
      }
    }
    __syncthreads();
    // gh1 partial = gu2 @ w1b^T  (cross-WG reduction R_b)
    {
      float acc[4]={0,0,0,0};
      #pragma unroll
      for (int jj=0;jj<4;jj++){
        float gj = gu2[j0+jj];
        #pragma unroll
        for (int ii=0;ii<4;ii++){
          float w = fmaf(pw1[1][jj*4+ii], cAp, mw1[1][jj*4+ii]*cBp);
          acc[ii] = fmaf(gj, w, acc[ii]);
        }
      }
      #pragma unroll
      for (int ii=0;ii<4;ii++) acc[ii] += __shfl_xor(acc[ii], 32, 64);
      if ((tid & 32)==0){
        int wv = tid>>6;
        #pragma unroll
        for (int ii=0;ii<4;ii++) redbuf[wv][i0+ii] = acc[ii];
      }
    }
    __syncthreads();
    if (tid < HD){
      float p=0.f;
      #pragma unroll
      for (int w_=0;w_<8;w_++) p += redbuf[w_][tid];
      __hip_atomic_store(&slotB[tid], p, __ATOMIC_RELAXED, __HIP_MEMORY_SCOPE_AGENT);
    }
    wgbar(cB_, tgtb); tgtb += 4;
    if (tid < HD){
      float s0 = g2v[tid];                 // residual path
      #pragma unroll
      for (int w_=0;w_<NWG;w_++) s0 += redload(0, w_, tid);
      gh1[tid] = s0;
    }
    __syncthreads();
    // gu1 = (gh1 @ w2a^T) * silu'(u1)
    {
      float acc[4]={0,0,0,0};
      #pragma unroll
      for (int oo=0;oo<4;oo++){
        float go = gh1[i0+oo];
        #pragma unroll
        for (int jj=0;jj<4;jj++){
          float w = fmaf(pw2[0][jj*4+oo], cAp, mw2[0][jj*4+oo]*cBp);
          acc[jj] = fmaf(go, w, acc[jj]);
        }
      }
      #pragma unroll
      for (int d=1; d<32; d<<=1){
        #pragma unroll
        for (int jj=0;jj<4;jj++) acc[jj] += __shfl_xor(acc[jj], d, 64);
      }
      if (iG==0){
        #pragma unroll
        for (int jj=0;jj<4;jj++){
          int j=j0+jj; float u=u1k[j]; float sg=sigm(u);
          gu1[j] = acc[jj]*sg*fmaf(u, 1.f-sg, 1.f);
        }
      }
    }
    __syncthreads();
    // ---- momentum update: m = eta*m - theta*grad (grads are outer products) ----
    {
      float th = scal[0], et = scal[2];
      #pragma unroll
      for (int jj=0;jj<4;jj++){
        float g1j = gu1[j0+jj], g2j = gu2[j0+jj];
        float s1j = s1k[j0+jj], s2j = s2k[j0+jj];
        #pragma unroll
        for (int ii=0;ii<4;ii++){
          int e = jj*4+ii;
          mw1[0][e] = fmaf(et, mw1[0][e], -th*(kvec[i0+ii]*g1j));
          mw1[1][e] = fmaf(et, mw1[1][e], -th*(h1k[i0+ii]*g2j));
          mw2[0][e] = fmaf(et, mw2[0][e], -th*(s1j*gh1[i0+ii]));
          mw2[1][e] = fmaf(et, mw2[1][e], -th*(s2j*g2v[i0+ii]));
        }
      }
      if (tid < CW){
        b1m[0][tid] = fmaf(et, b1m[0][tid], -th*gu1[tid]);
        b1m[1][tid] = fmaf(et, b1m[1][tid], -th*gu2[tid]);
      } else if (tid < CW+32){
        int oo = tid - CW;
        b2m[0][oo] = fmaf(et, b2m[0][oo], -th*gh1[wg*32+oo]);
        b2m[1][oo] = fmaf(et, b2m[1][oo], -th*g2v[wg*32+oo]);
      }
    }
    __syncthreads();
    // ---- merged forward: q_t (output) + k_{t+1}, with p_t = p0*(1-a_t) + m_t ----
    if (tid < HD){
      qvec[tid] = qbuf[((size_t)b*SEQ + t)*HD + tid];
      int tn = (t < SEQ-1) ? t+1 : SEQ-1;
      kvec[tid] = kbuf[((size_t)b*SEQ + tn)*HD + tid];
    }
    if (tid==0){ scal[5] = 1.f - scal[1]; scal[6] = 1.f; }
    __syncthreads();
    fwdDual(t, true);
  }
}

extern "C" void kernel_launch(void* const* d_in, const int* in_sizes, int n_in,
                              void* d_out, int out_size, void* d_ws, size_t ws_size,
                              hipStream_t stream)
{
  (void)in_sizes; (void)n_in; (void)out_size; (void)ws_size;
  const float* x    = (const float*)d_in[0];
  const float* Wq   = (const float*)d_in[1];
  const float* Wk   = (const float*)d_in[2];
  const float* Wv   = (const float*)d_in[3];
  const float* w_lr = (const float*)d_in[4];
  const float* b_lr = (const float*)d_in[5];
  const float* w_fg = (const float*)d_in[6];
  const float* b_fg = (const float*)d_in[7];
  const float* w_mo = (const float*)d_in[8];
  const float* b_mo = (const float*)d_in[9];
  const float* w1_0 = (const float*)d_in[10];
  const float* b1_0 = (const float*)d_in[11];
  const float* w2_0 = (const float*)d_in[12];
  const float* b2_0 = (const float*)d_in[13];
  const float* m_w1_0 = (const float*)d_in[14];
  const float* m_b1_0 = (const float*)d_in[15];
  const float* m_w2_0 = (const float*)d_in[16];
  const float* m_b2_0 = (const float*)d_in[17];
  const float* w1_1 = (const float*)d_in[18];
  const float* b1_1 = (const float*)d_in[19];
  const float* w2_1 = (const float*)d_in[20];
  const float* b2_1 = (const float*)d_in[21];
  const float* m_w1_1 = (const float*)d_in[22];
  const float* m_b1_1 = (const float*)d_in[23];
  const float* m_w2_1 = (const float*)d_in[24];
  const float* m_b2_1 = (const float*)d_in[25];

  float* wsf = (float*)d_ws;
  unsigned* cnt = (unsigned*)d_ws;          // 16 uints, zeroed below
  float* red  = wsf + 64;                   // 12288 floats of reduction slots
  float* qbuf = wsf + 16384;
  float* kbuf = qbuf + NB*SEQ*HD;
  float* vbuf = kbuf + NB*SEQ*HD;
  float* thb  = vbuf + NB*SEQ*HD;
  float* alb  = thb + NB*SEQ;
  float* etb  = alb + NB*SEQ;

  hipMemsetAsync(d_ws, 0, 256, stream);     // zero barrier counters

  qkv_kernel<<<dim3(NB*SEQ), dim3(HD), 0, stream>>>(
      x, Wq, Wk, Wv, w_lr, b_lr, w_fg, b_fg, w_mo, b_mo,
      qbuf, kbuf, vbuf, thb, alb, etb);

  scan_kernel<<<dim3(NB*NWG), dim3(512), 0, stream>>>(
      w1_0, b1_0, w2_0, b2_0, m_w1_0, m_b1_0, m_w2_0, m_b2_0,
      w1_1, b1_1, w2_1, b2_1, m_w1_1, m_b1_1, m_w2_1, m_b2_1,
      qbuf, kbuf, vbuf, thb, alb, etb,
      red, cnt, (float*)d_out);
}

// Round 2
// 4290.964 us; speedup vs baseline: 1.1278x; 1.1278x over previous
//
#include <hip/hip_runtime.h>

// NeuralMemory scan: B=4, S=256, H=128, EXP=2, DEPTH=2.
// Design: params never materialized (p_t = p0*(1-a_t) + m_t). Momentum m and
// p0 live in REGISTERS, sharded over the 256 hidden units across 4 WGs/batch
// (64 units each). Cross-WG: 3 vector reductions per step via agent-scope
// atomics + per-WG step-tagged flag barriers (NO threadfence -> no L2
// writeback/invalidate sweeps). Grid = 16 blocks x 512 thr.

constexpr int HD  = 128;   // H
constexpr int SEQ = 256;   // S
constexpr int NB  = 4;     // B
constexpr int ED  = 256;   // H*EXP
constexpr int CW  = 64;    // hidden units per WG per layer (ED/NWG)
constexpr int NWG = 4;     // workgroups per batch

__device__ __forceinline__ float sigm(float x){ return 1.0f/(1.0f+__expf(-x)); }

// ---------------- kernel 1: q/k/v + gate scalars ----------------
__global__ __launch_bounds__(128) void qkv_kernel(
    const float* __restrict__ x,
    const float* __restrict__ Wq, const float* __restrict__ Wk, const float* __restrict__ Wv,
    const float* __restrict__ w_lr, const float* __restrict__ b_lr,
    const float* __restrict__ w_fg, const float* __restrict__ b_fg,
    const float* __restrict__ w_mo, const float* __restrict__ b_mo,
    float* __restrict__ qb, float* __restrict__ kb, float* __restrict__ vb,
    float* __restrict__ thb, float* __restrict__ alb, float* __restrict__ etb)
{
  const int bs = blockIdx.x;          // b*SEQ + s
  const int o  = threadIdx.x;         // 0..127
  __shared__ float xl[HD];
  __shared__ float rb[HD];
  xl[o] = x[(size_t)bs*HD + o];
  __syncthreads();

  float aq=0.f, ak=0.f, av=0.f;
  #pragma unroll 8
  for (int i=0;i<HD;i++){
    float xi = xl[i];
    aq = fmaf(xi, Wq[i*HD+o], aq);
    ak = fmaf(xi, Wk[i*HD+o], ak);
    av = fmaf(xi, Wv[i*HD+o], av);
  }
  float sq_ = aq*sigm(aq);
  float sk_ = ak*sigm(ak);
  float sv_ = av*sigm(av);

  auto bsum = [&](float v)->float {
    rb[o] = v; __syncthreads();
    for (int st=64; st>0; st>>=1){
      if (o < st) rb[o] += rb[o+st];
      __syncthreads();
    }
    float r = rb[0];
    __syncthreads();
    return r;
  };

  float nq = bsum(sq_*sq_);
  float nk = bsum(sk_*sk_);
  float dl = bsum(xl[o]*w_lr[o]);
  float df = bsum(xl[o]*w_fg[o]);
  float dm = bsum(xl[o]*w_mo[o]);

  qb[(size_t)bs*HD+o] = sq_ / fmaxf(sqrtf(nq), 1e-12f);
  kb[(size_t)bs*HD+o] = sk_ / fmaxf(sqrtf(nk), 1e-12f);
  vb[(size_t)bs*HD+o] = sv_;
  if (o==0){
    thb[bs] = sigm(dl + b_lr[0]) * 0.01f;   // MAX_LR
    alb[bs] = sigm(df + b_fg[0]);
    etb[bs] = sigm(dm + b_mo[0]);
  }
}

// ---------------- kernel 2: the sequential scan ----------------
__global__ __launch_bounds__(512, 2) void scan_kernel(
    const float* __restrict__ w1_0g, const float* __restrict__ b1_0g,
    const float* __restrict__ w2_0g, const float* __restrict__ b2_0g,
    const float* __restrict__ mw1_0g, const float* __restrict__ mb1_0g,
    const float* __restrict__ mw2_0g, const float* __restrict__ mb2_0g,
    const float* __restrict__ w1_1g, const float* __restrict__ b1_1g,
    const float* __restrict__ w2_1g, const float* __restrict__ b2_1g,
    const float* __restrict__ mw1_1g, const float* __restrict__ mb1_1g,
    const float* __restrict__ mw2_1g, const float* __restrict__ mb2_1g,
    const float* __restrict__ qbuf, const float* __restrict__ kbuf, const float* __restrict__ vbuf,
    const float* __restrict__ thb, const float* __restrict__ alb, const float* __restrict__ etb,
    float* __restrict__ red, unsigned* __restrict__ flags, float* __restrict__ out)
{
  const int bid = blockIdx.x;
  const int b   = bid & 3;     // batch (blockIdx%4 -> spreads a batch's WGs over XCDs)
  const int wg  = bid >> 2;    // 0..3 within batch
  const int tid = threadIdx.x;
  const int iG  = tid & 31;    // i-group (w1) / o-group (w2)
  const int jG  = tid >> 5;    // j-group 0..15
  const int i0  = iG*4;
  const int j0  = jG*4;
  const int c0  = wg*CW;

  // ---- register-resident parameter slices: 64 m + 64 p0 per thread ----
  float mw1[2][16], pw1[2][16], mw2[2][16], pw2[2][16];
  {
    const float* w1s[2]  = {w1_0g,  w1_1g};
    const float* mw1s[2] = {mw1_0g, mw1_1g};
    const float* w2s[2]  = {w2_0g,  w2_1g};
    const float* mw2s[2] = {mw2_0g, mw2_1g};
    #pragma unroll
    for (int l=0;l<2;l++){
      #pragma unroll
      for (int jj=0;jj<4;jj++){
        #pragma unroll
        for (int ii=0;ii<4;ii++){
          int gi1 = (i0+ii)*ED + (c0+j0+jj);
          pw1[l][jj*4+ii] = w1s[l][gi1];
          mw1[l][jj*4+ii] = mw1s[l][gi1];
          int gi2 = (c0+j0+jj)*HD + (i0+ii);
          pw2[l][jj*4+ii] = w2s[l][gi2];
          mw2[l][jj*4+ii] = mw2s[l][gi2];
        }
      }
    }
  }

  __shared__ float kvec[HD], qvec[HD], vvec[HD];
  __shared__ float u1k[CW], u2k[CW], s1k[CW], s2k[CW], sq1[CW], sq2[CW];
  __shared__ float h1k[HD], h1q[HD], h2k[HD];
  __shared__ float g2v[HD], gh1[HD], gu1[CW], gu2[CW];
  __shared__ float redbuf[8][256];
  __shared__ float b1p[2][CW], b1m[2][CW], b2p[2][32], b2m[2][32];
  __shared__ float scal[8];   // [0]=theta [1]=alpha [2]=eta [5]=cA [6]=cB

  if (tid < CW){
    b1p[0][tid] = b1_0g[c0+tid]; b1m[0][tid] = mb1_0g[c0+tid];
    b1p[1][tid] = b1_1g[c0+tid]; b1m[1][tid] = mb1_1g[c0+tid];
  } else if (tid < CW+32){
    int oo = tid - CW;
    b2p[0][oo] = b2_0g[wg*32+oo]; b2m[0][oo] = mb2_0g[wg*32+oo];
    b2p[1][oo] = b2_1g[wg*32+oo]; b2m[1][oo] = mb2_1g[wg*32+oo];
  }

  float* slotB  = red + ((b*3+0)*NWG + wg)*256;
  float* slotF1 = red + ((b*3+1)*NWG + wg)*256;
  float* slotF2 = red + ((b*3+2)*NWG + wg)*256;
  // per-WG monotone flags: flags[(b*3+type)*4 + wg]
  unsigned sB = 0, sF1 = 0, sF2 = 0;

  // Barrier: data was published with agent-scope atomic stores; the first
  // __syncthreads() drains vmcnt(0) in every wave (structural to s_barrier),
  // so the relaxed flag store is ordered after data visibility. No
  // threadfence -> no buffer_wbl2/buffer_inv L2 sweeps. Lanes 0..3 poll the
  // 4 flags in parallel (one load instruction covers all four).
  auto wgbar = [&](int type, unsigned seq){
    __syncthreads();
    if (tid == 0){
      __hip_atomic_store(&flags[(b*3+type)*4 + wg], seq,
                         __ATOMIC_RELAXED, __HIP_MEMORY_SCOPE_AGENT);
    }
    if (tid < 4){
      while (__hip_atomic_load(&flags[(b*3+type)*4 + tid],
                               __ATOMIC_RELAXED, __HIP_MEMORY_SCOPE_AGENT) < seq) { }
    }
    __syncthreads();
  };

  auto redload = [&](int type, int w, int idx)->float{
    float* p = red + ((b*3+type)*NWG + w)*256 + idx;
    return __hip_atomic_load(p, __ATOMIC_RELAXED, __HIP_MEMORY_SCOPE_AGENT);
  };

  // merged forward of q_t (output) and k_{t+1} (next step's activations)
  auto fwdDual = [&](int t, bool writeOut){
    float cA = scal[5], cB = scal[6];
    // ---- layer0 u ----
    {
      float aq[4]={0,0,0,0}, ak[4]={0,0,0,0};
      #pragma unroll
      for (int ii=0;ii<4;ii++){
        float qi = qvec[i0+ii], ki = kvec[i0+ii];
        #pragma unroll
        for (int jj=0;jj<4;jj++){
          float w = fmaf(pw1[0][jj*4+ii], cA, mw1[0][jj*4+ii]*cB);
          aq[jj] = fmaf(qi, w, aq[jj]);
          ak[jj] = fmaf(ki, w, ak[jj]);
        }
      }
      #pragma unroll
      for (int d=1; d<32; d<<=1){
        #pragma unroll
        for (int jj=0;jj<4;jj++){
          aq[jj] += __shfl_xor(aq[jj], d, 64);
          ak[jj] += __shfl_xor(ak[jj], d, 64);
        }
      }
      if (iG==0){
        #pragma unroll
        for (int jj=0;jj<4;jj++){
          int j=j0+jj;
          float bb = fmaf(b1p[0][j], cA, b1m[0][j]*cB);
          float uq = aq[jj]+bb, uk = ak[jj]+bb;
          u1k[j]=uk; s1k[j]=uk*sigm(uk); sq1[j]=uq*sigm(uq);
        }
      }
    }
    __syncthreads();
    // ---- layer0 s@w2 partials ----
    {
      float aq[4]={0,0,0,0}, ak[4]={0,0,0,0};
      #pragma unroll
      for (int jj=0;jj<4;jj++){
        float sjq = sq1[j0+jj], sjk = s1k[j0+jj];
        #pragma unroll
        for (int oo=0;oo<4;oo++){
          float w = fmaf(pw2[0][jj*4+oo], cA, mw2[0][jj*4+oo]*cB);
          aq[oo] = fmaf(sjq, w, aq[oo]);
          ak[oo] = fmaf(sjk, w, ak[oo]);
        }
      }
      #pragma unroll
      for (int oo=0;oo<4;oo++){
        aq[oo] += __shfl_xor(aq[oo], 32, 64);
        ak[oo] += __shfl_xor(ak[oo], 32, 64);
      }
      if ((tid & 32)==0){
        int wv = tid>>6;
        #pragma unroll
        for (int oo=0;oo<4;oo++){
          redbuf[wv][i0+oo]     = aq[oo];
          redbuf[wv][128+i0+oo] = ak[oo];
        }
      }
    }
    __syncthreads();
    if (tid < 256){
      float p=0.f;
      #pragma unroll
      for (int w_=0; w_<8; w_++) p += redbuf[w_][tid];
      int o = tid & 127;
      if (o >= wg*32 && o < wg*32+32){
        int oo = o - wg*32;
        p += fmaf(b2p[0][oo], cA, b2m[0][oo]*cB);   // owner adds b2 shard
      }
      __hip_atomic_store(&slotF1[tid], p, __ATOMIC_RELAXED, __HIP_MEMORY_SCOPE_AGENT);
    }
    sF1++; wgbar(1, sF1);
    if (tid < 256){
      int o = tid & 127;
      float s0 = (tid<128) ? qvec[o] : kvec[o];     // residual
      #pragma unroll
      for (int w_=0; w_<NWG; w_++) s0 += redload(1, w_, tid);
      if (tid<128) h1q[o]=s0; else h1k[o]=s0;
    }
    __syncthreads();
    // ---- layer1 u ----
    {
      float aq[4]={0,0,0,0}, ak[4]={0,0,0,0};
      #pragma unroll
      for (int ii=0;ii<4;ii++){
        float qi = h1q[i0+ii], ki = h1k[i0+ii];
        #pragma unroll
        for (int jj=0;jj<4;jj++){
          float w = fmaf(pw1[1][jj*4+ii], cA, mw1[1][jj*4+ii]*cB);
          aq[jj] = fmaf(qi, w, aq[jj]);
          ak[jj] = fmaf(ki, w, ak[jj]);
        }
      }
      #pragma unroll
      for (int d=1; d<32; d<<=1){
        #pragma unroll
        for (int jj=0;jj<4;jj++){
          aq[jj] += __shfl_xor(aq[jj], d, 64);
          ak[jj] += __shfl_xor(ak[jj], d, 64);
        }
      }
      if (iG==0){
        #pragma unroll
        for (int jj=0;jj<4;jj++){
          int j=j0+jj;
          float bb = fmaf(b1p[1][j], cA, b1m[1][j]*cB);
          float uq = aq[jj]+bb, uk = ak[jj]+bb;
          u2k[j]=uk; s2k[j]=uk*sigm(uk); sq2[j]=uq*sigm(uq);
        }
      }
    }
    __syncthreads();
    // ---- layer1 s@w2 partials ----
    {
      float aq[4]={0,0,0,0}, ak[4]={0,0,0,0};
      #pragma unroll
      for (int jj=0;jj<4;jj++){
        float sjq = sq2[j0+jj], sjk = s2k[j0+jj];
        #pragma unroll
        for (int oo=0;oo<4;oo++){
          float w = fmaf(pw2[1][jj*4+oo], cA, mw2[1][jj*4+oo]*cB);
          aq[oo] = fmaf(sjq, w, aq[oo]);
          ak[oo] = fmaf(sjk, w, ak[oo]);
        }
      }
      #pragma unroll
      for (int oo=0;oo<4;oo++){
        aq[oo] += __shfl_xor(aq[oo], 32, 64);
        ak[oo] += __shfl_xor(ak[oo], 32, 64);
      }
      if ((tid & 32)==0){
        int wv = tid>>6;
        #pragma unroll
        for (int oo=0;oo<4;oo++){
          redbuf[wv][i0+oo]     = aq[oo];
          redbuf[wv][128+i0+oo] = ak[oo];
        }
      }
    }
    __syncthreads();
    if (tid < 256){
      float p=0.f;
      #pragma unroll
      for (int w_=0; w_<8; w_++) p += redbuf[w_][tid];
      int o = tid & 127;
      if (o >= wg*32 && o < wg*32+32){
        int oo = o - wg*32;
        p += fmaf(b2p[1][oo], cA, b2m[1][oo]*cB);
      }
      __hip_atomic_store(&slotF2[tid], p, __ATOMIC_RELAXED, __HIP_MEMORY_SCOPE_AGENT);
    }
    sF2++; wgbar(2, sF2);
    if (tid < 256){
      int o = tid & 127;
      float s0 = (tid<128) ? h1q[o] : h1k[o];
      #pragma unroll
      for (int w_=0; w_<NWG; w_++) s0 += redload(2, w_, tid);
      if (tid<128){
        if (writeOut && o >= wg*32 && o < wg*32+32)
          out[((size_t)(b*SEQ + t))*HD + o] = s0;   // y[b,t,:] shard
      } else {
        h2k[o] = s0;                                 // pred for next bwd
      }
    }
  };

  // ---- prologue: forward k_0 with cp = p0 exactly (cA=1, cB=0) ----
  if (tid < HD){
    kvec[tid] = kbuf[((size_t)b*SEQ + 0)*HD + tid];
    qvec[tid] = 0.f;
  }
  if (tid==0){ scal[5]=1.f; scal[6]=0.f; }
  __syncthreads();
  fwdDual(0, false);

  for (int t=0; t<SEQ; ++t){
    if (tid < HD) vvec[tid] = vbuf[((size_t)b*SEQ + t)*HD + tid];
    if (tid==0){
      scal[0]=thb[b*SEQ+t]; scal[1]=alb[b*SEQ+t]; scal[2]=etb[b*SEQ+t];
    }
    __syncthreads();
    float cAp = scal[5], cBp = scal[6];   // coefs of p_{t-1} (prev fwd)
    if (tid < HD) g2v[tid] = (2.0f/128.0f)*(h2k[tid]-vvec[tid]);
    __syncthreads();
    // gu2 = (g2 @ w2b^T) * silu'(u2)
    {
      float acc[4]={0,0,0,0};
      #pragma unroll
      for (int oo=0;oo<4;oo++){
        float go = g2v[i0+oo];
        #pragma unroll
        for (int jj=0;jj<4;jj++){
          float w = fmaf(pw2[1][jj*4+oo], cAp, mw2[1][jj*4+oo]*cBp);
          acc[jj] = fmaf(go, w, acc[jj]);
        }
      }
      #pragma unroll
      for (int d=1; d<32; d<<=1){
        #pragma unroll
        for (int jj=0;jj<4;jj++) acc[jj] += __shfl_xor(acc[jj], d, 64);
      }
      if (iG==0){
        #pragma unroll
        for (int jj=0;jj<4;jj++){
          int j=j0+jj; float u=u2k[j]; float sg=sigm(u);
          gu2[j] = acc[jj]*sg*fmaf(u, 1.f-sg, 1.f);
        }
      }
    }
    __syncthreads();
    // gh1 partial = gu2 @ w1b^T  (cross-WG reduction)
    {
      float acc[4]={0,0,0,0};
      #pragma unroll
      for (int jj=0;jj<4;jj++){
        float gj = gu2[j0+jj];
        #pragma unroll
        for (int ii=0;ii<4;ii++){
          float w = fmaf(pw1[1][jj*4+ii], cAp, mw1[1][jj*4+ii]*cBp);
          acc[ii] = fmaf(gj, w, acc[ii]);
        }
      }
      #pragma unroll
      for (int ii=0;ii<4;ii++) acc[ii] += __shfl_xor(acc[ii], 32, 64);
      if ((tid & 32)==0){
        int wv = tid>>6;
        #pragma unroll
        for (int ii=0;ii<4;ii++) redbuf[wv][i0+ii] = acc[ii];
      }
    }
    __syncthreads();
    if (tid < HD){
      float p=0.f;
      #pragma unroll
      for (int w_=0;w_<8;w_++) p += redbuf[w_][tid];
      __hip_atomic_store(&slotB[tid], p, __ATOMIC_RELAXED, __HIP_MEMORY_SCOPE_AGENT);
    }
    sB++; wgbar(0, sB);
    if (tid < HD){
      float s0 = g2v[tid];                 // residual path
      #pragma unroll
      for (int w_=0;w_<NWG;w_++) s0 += redload(0, w_, tid);
      gh1[tid] = s0;
    }
    __syncthreads();
    // gu1 = (gh1 @ w2a^T) * silu'(u1)
    {
      float acc[4]={0,0,0,0};
      #pragma unroll
      for (int oo=0;oo<4;oo++){
        float go = gh1[i0+oo];
        #pragma unroll
        for (int jj=0;jj<4;jj++){
          float w = fmaf(pw2[0][jj*4+oo], cAp, mw2[0][jj*4+oo]*cBp);
          acc[jj] = fmaf(go, w, acc[jj]);
        }
      }
      #pragma unroll
      for (int d=1; d<32; d<<=1){
        #pragma unroll
        for (int jj=0;jj<4;jj++) acc[jj] += __shfl_xor(acc[jj], d, 64);
      }
      if (iG==0){
        #pragma unroll
        for (int jj=0;jj<4;jj++){
          int j=j0+jj; float u=u1k[j]; float sg=sigm(u);
          gu1[j] = acc[jj]*sg*fmaf(u, 1.f-sg, 1.f);
        }
      }
    }
    __syncthreads();
    // ---- momentum update: m = eta*m - theta*grad (grads are outer products) ----
    {
      float th = scal[0], et = scal[2];
      #pragma unroll
      for (int jj=0;jj<4;jj++){
        float g1j = gu1[j0+jj], g2j = gu2[j0+jj];
        float s1j = s1k[j0+jj], s2j = s2k[j0+jj];
        #pragma unroll
        for (int ii=0;ii<4;ii++){
          int e = jj*4+ii;
          mw1[0][e] = fmaf(et, mw1[0][e], -th*(kvec[i0+ii]*g1j));
          mw1[1][e] = fmaf(et, mw1[1][e], -th*(h1k[i0+ii]*g2j));
          mw2[0][e] = fmaf(et, mw2[0][e], -th*(s1j*gh1[i0+ii]));
          mw2[1][e] = fmaf(et, mw2[1][e], -th*(s2j*g2v[i0+ii]));
        }
      }
      if (tid < CW){
        b1m[0][tid] = fmaf(et, b1m[0][tid], -th*gu1[tid]);
        b1m[1][tid] = fmaf(et, b1m[1][tid], -th*gu2[tid]);
      } else if (tid < CW+32){
        int oo = tid - CW;
        b2m[0][oo] = fmaf(et, b2m[0][oo], -th*gh1[wg*32+oo]);
        b2m[1][oo] = fmaf(et, b2m[1][oo], -th*g2v[wg*32+oo]);
      }
    }
    __syncthreads();
    // ---- merged forward: q_t (output) + k_{t+1}, with p_t = p0*(1-a_t) + m_t ----
    if (tid < HD){
      qvec[tid] = qbuf[((size_t)b*SEQ + t)*HD + tid];
      int tn = (t < SEQ-1) ? t+1 : SEQ-1;
      kvec[tid] = kbuf[((size_t)b*SEQ + tn)*HD + tid];
    }
    if (tid==0){ scal[5] = 1.f - scal[1]; scal[6] = 1.f; }
    __syncthreads();
    fwdDual(t, true);
  }
}

extern "C" void kernel_launch(void* const* d_in, const int* in_sizes, int n_in,
                              void* d_out, int out_size, void* d_ws, size_t ws_size,
                              hipStream_t stream)
{
  (void)in_sizes; (void)n_in; (void)out_size; (void)ws_size;
  const float* x    = (const float*)d_in[0];
  const float* Wq   = (const float*)d_in[1];
  const float* Wk   = (const float*)d_in[2];
  const float* Wv   = (const float*)d_in[3];
  const float* w_lr = (const float*)d_in[4];
  const float* b_lr = (const float*)d_in[5];
  const float* w_fg = (const float*)d_in[6];
  const float* b_fg = (const float*)d_in[7];
  const float* w_mo = (const float*)d_in[8];
  const float* b_mo = (const float*)d_in[9];
  const float* w1_0 = (const float*)d_in[10];
  const float* b1_0 = (const float*)d_in[11];
  const float* w2_0 = (const float*)d_in[12];
  const float* b2_0 = (const float*)d_in[13];
  const float* m_w1_0 = (const float*)d_in[14];
  const float* m_b1_0 = (const float*)d_in[15];
  const float* m_w2_0 = (const float*)d_in[16];
  const float* m_b2_0 = (const float*)d_in[17];
  const float* w1_1 = (const float*)d_in[18];
  const float* b1_1 = (const float*)d_in[19];
  const float* w2_1 = (const float*)d_in[20];
  const float* b2_1 = (const float*)d_in[21];
  const float* m_w1_1 = (const float*)d_in[22];
  const float* m_b1_1 = (const float*)d_in[23];
  const float* m_w2_1 = (const float*)d_in[24];
  const float* m_b2_1 = (const float*)d_in[25];

  float* wsf = (float*)d_ws;
  unsigned* flags = (unsigned*)d_ws;        // 48 uints, zeroed below
  float* red  = wsf + 64;                   // 12288 floats of reduction slots
  float* qbuf = wsf + 16384;
  float* kbuf = qbuf + NB*SEQ*HD;
  float* vbuf = kbuf + NB*SEQ*HD;
  float* thb  = vbuf + NB*SEQ*HD;
  float* alb  = thb + NB*SEQ;
  float* etb  = alb + NB*SEQ;

  hipMemsetAsync(d_ws, 0, 256, stream);     // zero barrier flags

  qkv_kernel<<<dim3(NB*SEQ), dim3(HD), 0, stream>>>(
      x, Wq, Wk, Wv, w_lr, b_lr, w_fg, b_fg, w_mo, b_mo,
      qbuf, kbuf, vbuf, thb, alb, etb);

  scan_kernel<<<dim3(NB*NWG), dim3(512), 0, stream>>>(
      w1_0, b1_0, w2_0, b2_0, m_w1_0, m_b1_0, m_w2_0, m_b2_0,
      w1_1, b1_1, w2_1, b2_1, m_w1_1, m_b1_1, m_w2_1, m_b2_1,
      qbuf, kbuf, vbuf, thb, alb, etb,
      red, flags, (float*)d_out);
}

// Round 3
// 3811.124 us; speedup vs baseline: 1.2698x; 1.1259x over previous
//
#include <hip/hip_runtime.h>

// NeuralMemory scan: B=4, S=256, H=128, EXP=2, DEPTH=2.
// p_t = p0*(1-a_t) + m_t -> params never materialized; momentum m and p0 live
// in REGISTERS, sharded over the 256 hidden units across 4 WGs/batch.
// Cross-WG exchange: each float is published as a 64-bit word (hi=seq tag,
// lo=payload) via relaxed agent-scope atomics; readers poll the words
// directly until tag==seq. No flags, no fences, no barrier syncthreads --
// one fabric round-trip per exchange. Grid = 16 blocks x 512 thr.

constexpr int HD  = 128;   // H
constexpr int SEQ = 256;   // S
constexpr int NB  = 4;     // B
constexpr int ED  = 256;   // H*EXP
constexpr int CW  = 64;    // hidden units per WG per layer (ED/NWG)
constexpr int NWG = 4;     // workgroups per batch

__device__ __forceinline__ float sigm(float x){ return 1.0f/(1.0f+__expf(-x)); }

// ---------------- kernel 1: q/k/v + gate scalars ----------------
__global__ __launch_bounds__(128) void qkv_kernel(
    const float* __restrict__ x,
    const float* __restrict__ Wq, const float* __restrict__ Wk, const float* __restrict__ Wv,
    const float* __restrict__ w_lr, const float* __restrict__ b_lr,
    const float* __restrict__ w_fg, const float* __restrict__ b_fg,
    const float* __restrict__ w_mo, const float* __restrict__ b_mo,
    float* __restrict__ qb, float* __restrict__ kb, float* __restrict__ vb,
    float* __restrict__ thb, float* __restrict__ alb, float* __restrict__ etb)
{
  const int bs = blockIdx.x;          // b*SEQ + s
  const int o  = threadIdx.x;         // 0..127
  __shared__ float xl[HD];
  __shared__ float rb[HD];
  xl[o] = x[(size_t)bs*HD + o];
  __syncthreads();

  float aq=0.f, ak=0.f, av=0.f;
  #pragma unroll 8
  for (int i=0;i<HD;i++){
    float xi = xl[i];
    aq = fmaf(xi, Wq[i*HD+o], aq);
    ak = fmaf(xi, Wk[i*HD+o], ak);
    av = fmaf(xi, Wv[i*HD+o], av);
  }
  float sq_ = aq*sigm(aq);
  float sk_ = ak*sigm(ak);
  float sv_ = av*sigm(av);

  auto bsum = [&](float v)->float {
    rb[o] = v; __syncthreads();
    for (int st=64; st>0; st>>=1){
      if (o < st) rb[o] += rb[o+st];
      __syncthreads();
    }
    float r = rb[0];
    __syncthreads();
    return r;
  };

  float nq = bsum(sq_*sq_);
  float nk = bsum(sk_*sk_);
  float dl = bsum(xl[o]*w_lr[o]);
  float df = bsum(xl[o]*w_fg[o]);
  float dm = bsum(xl[o]*w_mo[o]);

  qb[(size_t)bs*HD+o] = sq_ / fmaxf(sqrtf(nq), 1e-12f);
  kb[(size_t)bs*HD+o] = sk_ / fmaxf(sqrtf(nk), 1e-12f);
  vb[(size_t)bs*HD+o] = sv_;
  if (o==0){
    thb[bs] = sigm(dl + b_lr[0]) * 0.01f;   // MAX_LR
    alb[bs] = sigm(df + b_fg[0]);
    etb[bs] = sigm(dm + b_mo[0]);
  }
}

// ---------------- kernel 2: the sequential scan ----------------
__global__ __launch_bounds__(512, 2) void scan_kernel(
    const float* __restrict__ w1_0g, const float* __restrict__ b1_0g,
    const float* __restrict__ w2_0g, const float* __restrict__ b2_0g,
    const float* __restrict__ mw1_0g, const float* __restrict__ mb1_0g,
    const float* __restrict__ mw2_0g, const float* __restrict__ mb2_0g,
    const float* __restrict__ w1_1g, const float* __restrict__ b1_1g,
    const float* __restrict__ w2_1g, const float* __restrict__ b2_1g,
    const float* __restrict__ mw1_1g, const float* __restrict__ mb1_1g,
    const float* __restrict__ mw2_1g, const float* __restrict__ mb2_1g,
    const float* __restrict__ qbuf, const float* __restrict__ kbuf, const float* __restrict__ vbuf,
    const float* __restrict__ thb, const float* __restrict__ alb, const float* __restrict__ etb,
    unsigned long long* __restrict__ red, float* __restrict__ out)
{
  const int bid = blockIdx.x;
  const int b   = bid & 3;     // batch
  const int wg  = bid >> 2;    // 0..3 within batch
  const int tid = threadIdx.x;
  const int iG  = tid & 31;    // i-group (w1) / o-group (w2)
  const int jG  = tid >> 5;    // j-group 0..15
  const int i0  = iG*4;
  const int j0  = jG*4;
  const int c0  = wg*CW;

  // ---- register-resident parameter slices: 64 m + 64 p0 per thread ----
  float mw1[2][16], pw1[2][16], mw2[2][16], pw2[2][16];
  {
    const float* w1s[2]  = {w1_0g,  w1_1g};
    const float* mw1s[2] = {mw1_0g, mw1_1g};
    const float* w2s[2]  = {w2_0g,  w2_1g};
    const float* mw2s[2] = {mw2_0g, mw2_1g};
    #pragma unroll
    for (int l=0;l<2;l++){
      #pragma unroll
      for (int jj=0;jj<4;jj++){
        #pragma unroll
        for (int ii=0;ii<4;ii++){
          int gi1 = (i0+ii)*ED + (c0+j0+jj);
          pw1[l][jj*4+ii] = w1s[l][gi1];
          mw1[l][jj*4+ii] = mw1s[l][gi1];
          int gi2 = (c0+j0+jj)*HD + (i0+ii);
          pw2[l][jj*4+ii] = w2s[l][gi2];
          mw2[l][jj*4+ii] = mw2s[l][gi2];
        }
      }
    }
  }

  __shared__ float kvec[HD], qvec[HD], vvec[HD];
  __shared__ float u1k[CW], u2k[CW], s1k[CW], s2k[CW], sq1[CW], sq2[CW];
  __shared__ float h1k[HD], h1q[HD], h2k[HD];
  __shared__ float g2v[HD], gh1[HD], gu1[CW], gu2[CW];
  __shared__ float redbuf[8][256];
  __shared__ float b1p[2][CW], b1m[2][CW], b2p[2][32], b2m[2][32];
  __shared__ float scal[8];   // [0]=theta [1]=alpha [2]=eta [5]=cA [6]=cB

  if (tid < CW){
    b1p[0][tid] = b1_0g[c0+tid]; b1m[0][tid] = mb1_0g[c0+tid];
    b1p[1][tid] = b1_1g[c0+tid]; b1m[1][tid] = mb1_1g[c0+tid];
  } else if (tid < CW+32){
    int oo = tid - CW;
    b2p[0][oo] = b2_0g[wg*32+oo]; b2m[0][oo] = mb2_0g[wg*32+oo];
    b2p[1][oo] = b2_1g[wg*32+oo]; b2m[1][oo] = mb2_1g[wg*32+oo];
  }

  // publish: one 64-bit word = (seq<<32) | float bits.  relaxed agent scope.
  auto pubstore = [&](int type, unsigned seq, int idx, float val){
    unsigned long long* p = red + (((b*3+type)*NWG + wg)*256 + idx);
    unsigned long long pk = ((unsigned long long)seq << 32) |
                            (unsigned long long)__float_as_uint(val);
    __hip_atomic_store(p, pk, __ATOMIC_RELAXED, __HIP_MEMORY_SCOPE_AGENT);
  };
  // poll the 3 remote WGs' words for this idx until tag==seq; sum payloads.
  auto pollacc = [&](int type, unsigned seq, int idx, float own)->float{
    unsigned long long* base = red + ((b*3+type)*NWG)*256;
    const int wA=((wg+1)&3)*256+idx, wB=((wg+2)&3)*256+idx, wC=((wg+3)&3)*256+idx;
    unsigned long long vA = __hip_atomic_load(base+wA, __ATOMIC_RELAXED, __HIP_MEMORY_SCOPE_AGENT);
    unsigned long long vB = __hip_atomic_load(base+wB, __ATOMIC_RELAXED, __HIP_MEMORY_SCOPE_AGENT);
    unsigned long long vC = __hip_atomic_load(base+wC, __ATOMIC_RELAXED, __HIP_MEMORY_SCOPE_AGENT);
    float s = own; unsigned got = 0;
    while (got != 7u){
      if (!(got&1u)){
        if ((unsigned)(vA>>32)==seq){ s += __uint_as_float((unsigned)vA); got|=1u; }
        else vA = __hip_atomic_load(base+wA, __ATOMIC_RELAXED, __HIP_MEMORY_SCOPE_AGENT);
      }
      if (!(got&2u)){
        if ((unsigned)(vB>>32)==seq){ s += __uint_as_float((unsigned)vB); got|=2u; }
        else vB = __hip_atomic_load(base+wB, __ATOMIC_RELAXED, __HIP_MEMORY_SCOPE_AGENT);
      }
      if (!(got&4u)){
        if ((unsigned)(vC>>32)==seq){ s += __uint_as_float((unsigned)vC); got|=4u; }
        else vC = __hip_atomic_load(base+wC, __ATOMIC_RELAXED, __HIP_MEMORY_SCOPE_AGENT);
      }
    }
    return s;
  };

  // merged forward of q_t (output) and k_{t+1}
  auto fwdDual = [&](int t, bool writeOut, unsigned seq){
    float cA = scal[5], cB = scal[6];
    // ---- layer0 u ----
    {
      float aq[4]={0,0,0,0}, ak[4]={0,0,0,0};
      #pragma unroll
      for (int ii=0;ii<4;ii++){
        float qi = qvec[i0+ii], ki = kvec[i0+ii];
        #pragma unroll
        for (int jj=0;jj<4;jj++){
          float w = fmaf(pw1[0][jj*4+ii], cA, mw1[0][jj*4+ii]*cB);
          aq[jj] = fmaf(qi, w, aq[jj]);
          ak[jj] = fmaf(ki, w, ak[jj]);
        }
      }
      #pragma unroll
      for (int d=1; d<32; d<<=1){
        #pragma unroll
        for (int jj=0;jj<4;jj++){
          aq[jj] += __shfl_xor(aq[jj], d, 64);
          ak[jj] += __shfl_xor(ak[jj], d, 64);
        }
      }
      if (iG==0){
        #pragma unroll
        for (int jj=0;jj<4;jj++){
          int j=j0+jj;
          float bb = fmaf(b1p[0][j], cA, b1m[0][j]*cB);
          float uq = aq[jj]+bb, uk = ak[jj]+bb;
          u1k[j]=uk; s1k[j]=uk*sigm(uk); sq1[j]=uq*sigm(uq);
        }
      }
    }
    __syncthreads();
    // ---- layer0 s@w2 partials ----
    {
      float aq[4]={0,0,0,0}, ak[4]={0,0,0,0};
      #pragma unroll
      for (int jj=0;jj<4;jj++){
        float sjq = sq1[j0+jj], sjk = s1k[j0+jj];
        #pragma unroll
        for (int oo=0;oo<4;oo++){
          float w = fmaf(pw2[0][jj*4+oo], cA, mw2[0][jj*4+oo]*cB);
          aq[oo] = fmaf(sjq, w, aq[oo]);
          ak[oo] = fmaf(sjk, w, ak[oo]);
        }
      }
      #pragma unroll
      for (int oo=0;oo<4;oo++){
        aq[oo] += __shfl_xor(aq[oo], 32, 64);
        ak[oo] += __shfl_xor(ak[oo], 32, 64);
      }
      if ((tid & 32)==0){
        int wv = tid>>6;
        #pragma unroll
        for (int oo=0;oo<4;oo++){
          redbuf[wv][i0+oo]     = aq[oo];
          redbuf[wv][128+i0+oo] = ak[oo];
        }
      }
    }
    __syncthreads();
    if (tid < 256){
      float p=0.f;
      #pragma unroll
      for (int w_=0; w_<8; w_++) p += redbuf[w_][tid];
      int o = tid & 127;
      if (o >= wg*32 && o < wg*32+32){
        int oo = o - wg*32;
        p += fmaf(b2p[0][oo], cA, b2m[0][oo]*cB);   // owner adds b2 shard
      }
      pubstore(1, seq, tid, p);
      float s0 = ((tid<128) ? qvec[o] : kvec[o]) + pollacc(1, seq, tid, p);
      if (tid<128) h1q[o]=s0; else h1k[o]=s0;
    }
    __syncthreads();
    // ---- layer1 u ----
    {
      float aq[4]={0,0,0,0}, ak[4]={0,0,0,0};
      #pragma unroll
      for (int ii=0;ii<4;ii++){
        float qi = h1q[i0+ii], ki = h1k[i0+ii];
        #pragma unroll
        for (int jj=0;jj<4;jj++){
          float w = fmaf(pw1[1][jj*4+ii], cA, mw1[1][jj*4+ii]*cB);
          aq[jj] = fmaf(qi, w, aq[jj]);
          ak[jj] = fmaf(ki, w, ak[jj]);
        }
      }
      #pragma unroll
      for (int d=1; d<32; d<<=1){
        #pragma unroll
        for (int jj=0;jj<4;jj++){
          aq[jj] += __shfl_xor(aq[jj], d, 64);
          ak[jj] += __shfl_xor(ak[jj], d, 64);
        }
      }
      if (iG==0){
        #pragma unroll
        for (int jj=0;jj<4;jj++){
          int j=j0+jj;
          float bb = fmaf(b1p[1][j], cA, b1m[1][j]*cB);
          float uq = aq[jj]+bb, uk = ak[jj]+bb;
          u2k[j]=uk; s2k[j]=uk*sigm(uk); sq2[j]=uq*sigm(uq);
        }
      }
    }
    __syncthreads();
    // ---- layer1 s@w2 partials ----
    {
      float aq[4]={0,0,0,0}, ak[4]={0,0,0,0};
      #pragma unroll
      for (int jj=0;jj<4;jj++){
        float sjq = sq2[j0+jj], sjk = s2k[j0+jj];
        #pragma unroll
        for (int oo=0;oo<4;oo++){
          float w = fmaf(pw2[1][jj*4+oo], cA, mw2[1][jj*4+oo]*cB);
          aq[oo] = fmaf(sjq, w, aq[oo]);
          ak[oo] = fmaf(sjk, w, ak[oo]);
        }
      }
      #pragma unroll
      for (int oo=0;oo<4;oo++){
        aq[oo] += __shfl_xor(aq[oo], 32, 64);
        ak[oo] += __shfl_xor(ak[oo], 32, 64);
      }
      if ((tid & 32)==0){
        int wv = tid>>6;
        #pragma unroll
        for (int oo=0;oo<4;oo++){
          redbuf[wv][i0+oo]     = aq[oo];
          redbuf[wv][128+i0+oo] = ak[oo];
        }
      }
    }
    __syncthreads();
    if (tid < 256){
      float p=0.f;
      #pragma unroll
      for (int w_=0; w_<8; w_++) p += redbuf[w_][tid];
      int o = tid & 127;
      if (o >= wg*32 && o < wg*32+32){
        int oo = o - wg*32;
        p += fmaf(b2p[1][oo], cA, b2m[1][oo]*cB);
      }
      pubstore(2, seq, tid, p);
      float s0 = ((tid<128) ? h1q[o] : h1k[o]) + pollacc(2, seq, tid, p);
      if (tid<128){
        if (writeOut && o >= wg*32 && o < wg*32+32)
          out[((size_t)(b*SEQ + t))*HD + o] = s0;   // y[b,t,:] shard
      } else {
        h2k[o] = s0;                                 // pred for next bwd
      }
    }
  };

  // ---- prologue: forward k_0 with cp = p0 exactly (cA=1, cB=0) ----
  if (tid < HD){
    kvec[tid] = kbuf[((size_t)b*SEQ + 0)*HD + tid];
    qvec[tid] = 0.f;
  }
  if (tid==0){ scal[5]=1.f; scal[6]=0.f; }
  __syncthreads();
  fwdDual(0, false, 1u);

  for (int t=0; t<SEQ; ++t){
    if (tid < HD) vvec[tid] = vbuf[((size_t)b*SEQ + t)*HD + tid];
    if (tid==0){
      scal[0]=thb[b*SEQ+t]; scal[1]=alb[b*SEQ+t]; scal[2]=etb[b*SEQ+t];
    }
    __syncthreads();
    float cAp = scal[5], cBp = scal[6];   // coefs of p_{t-1} (prev fwd)
    if (tid < HD) g2v[tid] = (2.0f/128.0f)*(h2k[tid]-vvec[tid]);
    __syncthreads();
    // gu2 = (g2 @ w2b^T) * silu'(u2)
    {
      float acc[4]={0,0,0,0};
      #pragma unroll
      for (int oo=0;oo<4;oo++){
        float go = g2v[i0+oo];
        #pragma unroll
        for (int jj=0;jj<4;jj++){
          float w = fmaf(pw2[1][jj*4+oo], cAp, mw2[1][jj*4+oo]*cBp);
          acc[jj] = fmaf(go, w, acc[jj]);
        }
      }
      #pragma unroll
      for (int d=1; d<32; d<<=1){
        #pragma unroll
        for (int jj=0;jj<4;jj++) acc[jj] += __shfl_xor(acc[jj], d, 64);
      }
      if (iG==0){
        #pragma unroll
        for (int jj=0;jj<4;jj++){
          int j=j0+jj; float u=u2k[j]; float sg=sigm(u);
          gu2[j] = acc[jj]*sg*fmaf(u, 1.f-sg, 1.f);
        }
      }
    }
    __syncthreads();
    // gh1 partial = gu2 @ w1b^T  (cross-WG exchange, type 0)
    {
      float acc[4]={0,0,0,0};
      #pragma unroll
      for (int jj=0;jj<4;jj++){
        float gj = gu2[j0+jj];
        #pragma unroll
        for (int ii=0;ii<4;ii++){
          float w = fmaf(pw1[1][jj*4+ii], cAp, mw1[1][jj*4+ii]*cBp);
          acc[ii] = fmaf(gj, w, acc[ii]);
        }
      }
      #pragma unroll
      for (int ii=0;ii<4;ii++) acc[ii] += __shfl_xor(acc[ii], 32, 64);
      if ((tid & 32)==0){
        int wv = tid>>6;
        #pragma unroll
        for (int ii=0;ii<4;ii++) redbuf[wv][i0+ii] = acc[ii];
      }
    }
    __syncthreads();
    {
      unsigned seqB = (unsigned)(t+1);
      if (tid < HD){
        float p=0.f;
        #pragma unroll
        for (int w_=0;w_<8;w_++) p += redbuf[w_][tid];
        pubstore(0, seqB, tid, p);
        gh1[tid] = g2v[tid] + pollacc(0, seqB, tid, p);
      }
    }
    __syncthreads();
    // gu1 = (gh1 @ w2a^T) * silu'(u1)
    {
      float acc[4]={0,0,0,0};
      #pragma unroll
      for (int oo=0;oo<4;oo++){
        float go = gh1[i0+oo];
        #pragma unroll
        for (int jj=0;jj<4;jj++){
          float w = fmaf(pw2[0][jj*4+oo], cAp, mw2[0][jj*4+oo]*cBp);
          acc[jj] = fmaf(go, w, acc[jj]);
        }
      }
      #pragma unroll
      for (int d=1; d<32; d<<=1){
        #pragma unroll
        for (int jj=0;jj<4;jj++) acc[jj] += __shfl_xor(acc[jj], d, 64);
      }
      if (iG==0){
        #pragma unroll
        for (int jj=0;jj<4;jj++){
          int j=j0+jj; float u=u1k[j]; float sg=sigm(u);
          gu1[j] = acc[jj]*sg*fmaf(u, 1.f-sg, 1.f);
        }
      }
    }
    __syncthreads();
    // ---- momentum update: m = eta*m - theta*grad (grads are outer products) ----
    {
      float th = scal[0], et = scal[2];
      #pragma unroll
      for (int jj=0;jj<4;jj++){
        float g1j = gu1[j0+jj], g2j = gu2[j0+jj];
        float s1j = s1k[j0+jj], s2j = s2k[j0+jj];
        #pragma unroll
        for (int ii=0;ii<4;ii++){
          int e = jj*4+ii;
          mw1[0][e] = fmaf(et, mw1[0][e], -th*(kvec[i0+ii]*g1j));
          mw1[1][e] = fmaf(et, mw1[1][e], -th*(h1k[i0+ii]*g2j));
          mw2[0][e] = fmaf(et, mw2[0][e], -th*(s1j*gh1[i0+ii]));
          mw2[1][e] = fmaf(et, mw2[1][e], -th*(s2j*g2v[i0+ii]));
        }
      }
      if (tid < CW){
        b1m[0][tid] = fmaf(et, b1m[0][tid], -th*gu1[tid]);
        b1m[1][tid] = fmaf(et, b1m[1][tid], -th*gu2[tid]);
      } else if (tid < CW+32){
        int oo = tid - CW;
        b2m[0][oo] = fmaf(et, b2m[0][oo], -th*gh1[wg*32+oo]);
        b2m[1][oo] = fmaf(et, b2m[1][oo], -th*g2v[wg*32+oo]);
      }
    }
    __syncthreads();
    // ---- merged forward: q_t (output) + k_{t+1}, p_t = p0*(1-a_t) + m_t ----
    if (tid < HD){
      qvec[tid] = qbuf[((size_t)b*SEQ + t)*HD + tid];
      int tn = (t < SEQ-1) ? t+1 : SEQ-1;
      kvec[tid] = kbuf[((size_t)b*SEQ + tn)*HD + tid];
    }
    if (tid==0){ scal[5] = 1.f - scal[1]; scal[6] = 1.f; }
    __syncthreads();
    fwdDual(t, true, (unsigned)(t+2));
  }
}

extern "C" void kernel_launch(void* const* d_in, const int* in_sizes, int n_in,
                              void* d_out, int out_size, void* d_ws, size_t ws_size,
                              hipStream_t stream)
{
  (void)in_sizes; (void)n_in; (void)out_size; (void)ws_size;
  const float* x    = (const float*)d_in[0];
  const float* Wq   = (const float*)d_in[1];
  const float* Wk   = (const float*)d_in[2];
  const float* Wv   = (const float*)d_in[3];
  const float* w_lr = (const float*)d_in[4];
  const float* b_lr = (const float*)d_in[5];
  const float* w_fg = (const float*)d_in[6];
  const float* b_fg = (const float*)d_in[7];
  const float* w_mo = (const float*)d_in[8];
  const float* b_mo = (const float*)d_in[9];
  const float* w1_0 = (const float*)d_in[10];
  const float* b1_0 = (const float*)d_in[11];
  const float* w2_0 = (const float*)d_in[12];
  const float* b2_0 = (const float*)d_in[13];
  const float* m_w1_0 = (const float*)d_in[14];
  const float* m_b1_0 = (const float*)d_in[15];
  const float* m_w2_0 = (const float*)d_in[16];
  const float* m_b2_0 = (const float*)d_in[17];
  const float* w1_1 = (const float*)d_in[18];
  const float* b1_1 = (const float*)d_in[19];
  const float* w2_1 = (const float*)d_in[20];
  const float* b2_1 = (const float*)d_in[21];
  const float* m_w1_1 = (const float*)d_in[22];
  const float* m_b1_1 = (const float*)d_in[23];
  const float* m_w2_1 = (const float*)d_in[24];
  const float* m_b2_1 = (const float*)d_in[25];

  float* wsf = (float*)d_ws;
  // 64-bit tagged exchange slots: 4 batches x 3 types x 4 WGs x 256 words
  unsigned long long* red = (unsigned long long*)d_ws;   // 98304 B
  float* qbuf = wsf + 32768;
  float* kbuf = qbuf + NB*SEQ*HD;
  float* vbuf = kbuf + NB*SEQ*HD;
  float* thb  = vbuf + NB*SEQ*HD;
  float* alb  = thb + NB*SEQ;
  float* etb  = alb + NB*SEQ;
  // No memset needed: ws is re-poisoned to 0xAA before every launch, and
  // 0xAAAAAAAA never equals a valid seq tag (tags are 1..257).

  qkv_kernel<<<dim3(NB*SEQ), dim3(HD), 0, stream>>>(
      x, Wq, Wk, Wv, w_lr, b_lr, w_fg, b_fg, w_mo, b_mo,
      qbuf, kbuf, vbuf, thb, alb, etb);

  scan_kernel<<<dim3(NB*NWG), dim3(512), 0, stream>>>(
      w1_0, b1_0, w2_0, b2_0, m_w1_0, m_b1_0, m_w2_0, m_b2_0,
      w1_1, b1_1, w2_1, b2_1, m_w1_1, m_b1_1, m_w2_1, m_b2_1,
      qbuf, kbuf, vbuf, thb, alb, etb,
      red, (float*)d_out);
}